// Round 7
// baseline (2161.683 us; speedup 1.0000x reference)
//
#include <hip/hip_runtime.h>
#include <hip/hip_bf16.h>

#define N_NODES 30000
#define N_EDGES 120000
#define IN_DIM  9
#define H       32
#define G_GRAPHS 256
#define NSTEP   66            // K = 33*32 = 1056, K-step 16
#define NBLK    512
#define NTHR    256
#define GSZ     (NBLK * NTHR) // 131072
#define NWAVE   (NBLK * 4)    // 2048
#define NTILE   3750          // 120000 / 32 edges per M-tile

typedef __attribute__((ext_vector_type(8)))  short short8v;
typedef __attribute__((ext_vector_type(4)))  unsigned int uint4v;
typedef __attribute__((ext_vector_type(16))) float f32x16;

__device__ __forceinline__ unsigned short bfb(float x) {
    __hip_bfloat16 h = __float2bfloat16(x);
    unsigned short r;
    __builtin_memcpy(&r, &h, 2);
    return r;
}
__device__ __forceinline__ float b2f(unsigned short u) {
    unsigned int x = ((unsigned int)u) << 16;
    return __builtin_bit_cast(float, x);
}
// pack two f32 -> packed bf16x2 (v_cvt_pk_bf16_f32)
__device__ __forceinline__ unsigned int pkbf(float lo, float hi) {
    float2 f; f.x = lo; f.y = hi;
    __hip_bfloat162 b = __float22bfloat162_rn(f);
    unsigned int r;
    __builtin_memcpy(&r, &b, 4);
    return r;
}

// device-scope generation barrier. bar[0]=count, bar[1]=generation.
// Requires all NBLK blocks co-resident (guaranteed: launch_bounds(256,4)
// -> VGPR<=128 -> >=4 blocks/CU capacity = 1024 >= 2*NBLK).
__device__ __forceinline__ void gbar(int* cnt, int* gen) {
    __syncthreads();
    if (threadIdx.x == 0) {
        __threadfence();  // release prior writes to device scope
        int g = __hip_atomic_load(gen, __ATOMIC_RELAXED, __HIP_MEMORY_SCOPE_AGENT);
        int a = __hip_atomic_fetch_add(cnt, 1, __ATOMIC_ACQ_REL, __HIP_MEMORY_SCOPE_AGENT);
        if (a == NBLK - 1) {
            __hip_atomic_store(cnt, 0, __ATOMIC_RELAXED, __HIP_MEMORY_SCOPE_AGENT);
            __hip_atomic_fetch_add(gen, 1, __ATOMIC_RELEASE, __HIP_MEMORY_SCOPE_AGENT);
        } else {
            while (__hip_atomic_load(gen, __ATOMIC_ACQUIRE, __HIP_MEMORY_SCOPE_AGENT) == g)
                __builtin_amdgcn_s_sleep(2);
        }
        __threadfence();
    }
    __syncthreads();
}

__global__ __launch_bounds__(NTHR, 4) void mega_k(
    const float* __restrict__ x, const int* __restrict__ ei,
    const float* __restrict__ eattr, const int* __restrict__ batch,
    const float* __restrict__ Wn, const float* __restrict__ bn,
    const float* __restrict__ We, const float* __restrict__ be,
    const float* __restrict__ Wnn, const float* __restrict__ bnn,
    const float* __restrict__ Wroot, const float* __restrict__ bconv,
    const float* __restrict__ W1, const float* __restrict__ b1,
    const float* __restrict__ W2, const float* __restrict__ b2,
    const float* __restrict__ W3, const float* __restrict__ b3,
    float* __restrict__ out,
    float* s0, float* s1, int* hist, float* pooled, int* cursor,
    int* rank, unsigned short* bfrag, unsigned short* msg, int* bar)
{
    const int tid  = threadIdx.x;
    const int gtid = blockIdx.x * NTHR + tid;
    const int* dst = ei + N_EDGES;
    int* cnt = bar; int* gen = bar + 1;

    __shared__ int   ws4[4];
    __shared__ float pP[H];
    __shared__ float ph1[128];
    __shared__ float ph2[64];

    // ---- P0: zero hist + pooled --------------------------------------
    for (int i = gtid; i < N_NODES + G_GRAPHS * H; i += GSZ) {
        if (i < N_NODES) hist[i] = 0;
        else             pooled[i - N_NODES] = 0.f;
    }
    gbar(cnt, gen);

    // ---- P1: node embed | weight frag conv | dst histogram -----------
    for (int gid = gtid; gid < N_NODES * H; gid += GSZ) {
        int n = gid >> 5, o = gid & 31;
        float acc = bn[o];
        #pragma unroll
        for (int i = 0; i < IN_DIM; ++i)
            acc = fmaf(x[n * IN_DIM + i], Wn[i * H + o], acc);
        s0[gid] = fmaxf(acc, 0.f);
    }
    for (int gid = gtid; gid < 3 * NSTEP * 512; gid += GSZ) {
        int layer = gid / (NSTEP * 512);
        int rem   = gid % (NSTEP * 512);
        int step  = rem >> 9;
        int lane  = (rem >> 3) & 63;
        int t     = gid & 7;
        int krow  = step * 16 + ((lane >> 5) << 3) + t;   // 0..1055
        int col   = lane & 31;
        float v = (krow < 1024) ? Wnn[layer * 32768 + krow * 32 + col]
                                : bnn[layer * 1024 + (krow - 1024) * 32 + col];
        bfrag[gid] = bfb(v);
    }
    for (int e = gtid; e < N_EDGES; e += GSZ)
        atomicAdd(&hist[dst[e]], 1);
    gbar(cnt, gen);

    // ---- P2: exclusive scan (block 0 only, 2-pass, no big reg arrays)
    if (blockIdx.x == 0) {
        const int CH = 118;                 // 256*118 = 30208 >= 30000
        const int base = tid * CH;
        int sum = 0;
        for (int i = 0; i < CH; ++i) {
            int idx = base + i;
            if (idx < N_NODES) sum += hist[idx];
        }
        const int lane = tid & 63, wid = tid >> 6;
        int incl = sum;
        #pragma unroll
        for (int off = 1; off < 64; off <<= 1) {
            int tmp = __shfl_up(incl, off);
            if (lane >= off) incl += tmp;
        }
        if (lane == 63) ws4[wid] = incl;
        __syncthreads();
        int woff = 0;
        for (int w = 0; w < wid; ++w) woff += ws4[w];
        int run = incl - sum + woff;        // exclusive prefix for this thread
        for (int i = 0; i < CH; ++i) {
            int idx = base + i;
            if (idx < N_NODES) { cursor[idx] = run; run += hist[idx]; }
        }
    }
    gbar(cnt, gen);

    // ---- P3: ranks (cursor becomes end-ptrs) --------------------------
    for (int e = gtid; e < N_EDGES; e += GSZ)
        rank[e] = atomicAdd(&cursor[dst[e]], 1);
    gbar(cnt, gen);

    // ---- layers --------------------------------------------------------
    const float* sin = s0;
    float* sout = s1;
    for (int k = 0; k < 3; ++k) {
        const unsigned short* bf = bfrag + k * NSTEP * 512;
        // edge conv: one 32-edge M-tile per wave, grid-stride over tiles.
        // A-frag: row=lane&31 (edge), k=(lane>>5)*8+t
        // D-frag: col=lane&31 (=o), row=(reg&3)+8*(reg>>2)+4*(lane>>5)
        const int wvid = (blockIdx.x << 2) + (tid >> 6);
        const int lane = tid & 63;
        const int er = lane & 31;
        const int hi = lane >> 5;
        for (int tile = wvid; tile < NTILE; tile += NWAVE) {
            const int ebase = tile * 32;
            const int e = ebase + er;
            const float a0v = eattr[e*3+0], a1v = eattr[e*3+1], a2v = eattr[e*3+2];
            const int src = ei[e];
            const int rk = rank[e];
            float h[16];
            {
                const float* r0 = sin + src * H + hi * 8;
                #pragma unroll
                for (int q = 0; q < 2; ++q) {
                    float4 u0 = *(const float4*)(r0 + q * 16);
                    float4 u1 = *(const float4*)(r0 + q * 16 + 4);
                    h[q*8+0]=u0.x; h[q*8+1]=u0.y; h[q*8+2]=u0.z; h[q*8+3]=u0.w;
                    h[q*8+4]=u1.x; h[q*8+5]=u1.y; h[q*8+6]=u1.z; h[q*8+7]=u1.w;
                }
            }
            f32x16 acc = {};
            float ea = 1.f;
            #pragma unroll
            for (int step = 0; step < NSTEP; ++step) {
                const int j = step >> 1;
                if ((step & 1) == 0) {
                    if (j < 32) {
                        const float w0 = We[j], w1 = We[32+j], w2 = We[64+j], bb = be[j];
                        ea = fmaxf(fmaf(a2v, w2, fmaf(a1v, w1, fmaf(a0v, w0, bb))), 0.f);
                    } else ea = 1.f;
                }
                const int hb = (step & 1) * 8;
                uint4v ai;
                #pragma unroll
                for (int q = 0; q < 4; ++q)
                    ai[q] = pkbf(ea * h[hb + 2*q], ea * h[hb + 2*q + 1]);
                const short8v A = __builtin_bit_cast(short8v, ai);
                const short8v B = *(const short8v*)(bf + ((step * 64 + lane) << 3));
                acc = __builtin_amdgcn_mfma_f32_32x32x16_bf16(A, B, acc, 0, 0, 0);
            }
            #pragma unroll
            for (int reg = 0; reg < 16; ++reg) {
                const int r = (reg & 3) + 8 * (reg >> 2) + 4 * hi;
                const int p = __shfl(rk, r);
                msg[p * H + er] = bfb(acc[reg]);
            }
        }
        gbar(cnt, gen);

        // finalize: gather(contiguous) + root + relu + residual (+pool last)
        for (int gid = gtid; gid < N_NODES * H; gid += GSZ) {
            int n = gid >> 5, o = gid & 31;
            float acc = bconv[k * H + o];
            const float* row = sin + n * H;
            #pragma unroll
            for (int i = 0; i < H; ++i)
                acc = fmaf(row[i], Wroot[k * H * H + i * H + o], acc);
            const int p0 = (n == 0) ? 0 : cursor[n - 1];
            const int p1 = cursor[n];
            for (int p = p0; p < p1; ++p)
                acc += b2f(msg[p * H + o]);
            float val = fmaxf(acc, 0.f) + sin[gid];
            if (k == 2) atomicAdd(pooled + batch[n] * H + o, val);
            else        sout[gid] = val;
        }
        gbar(cnt, gen);
        const float* tmp = sout; sout = (float*)sin; sin = tmp;
    }

    // ---- MLP head: blocks 0..255, one graph each ----------------------
    if (blockIdx.x < G_GRAPHS) {
        const int g = blockIdx.x, t = tid;
        if (t < H) pP[t] = pooled[g * H + t];
        __syncthreads();
        if (t < 128) {
            float a = b1[t];
            #pragma unroll
            for (int i = 0; i < H; ++i)
                a = fmaf(pP[i], W1[i * 128 + t], a);
            ph1[t] = fmaxf(a, 0.f);
        }
        __syncthreads();
        if (t < 64) {
            float a2 = b2[t];
            #pragma unroll 4
            for (int i = 0; i < 128; ++i)
                a2 = fmaf(ph1[i], W2[i * 64 + t], a2);
            ph2[t] = fmaxf(a2, 0.f);
        }
        __syncthreads();
        if (t < 64) {
            float v = ph2[t] * W3[t];
            #pragma unroll
            for (int off = 32; off > 0; off >>= 1)
                v += __shfl_down(v, off);
            if (t == 0) out[g] = v + b3[0];
        }
    }
}

// ---------------------------------------------------------------- launcher
extern "C" void kernel_launch(void* const* d_in, const int* in_sizes, int n_in,
                              void* d_out, int out_size, void* d_ws, size_t ws_size,
                              hipStream_t stream)
{
    const float* x     = (const float*)d_in[0];
    const int*   ei    = (const int*)  d_in[1];
    const float* eattr = (const float*)d_in[2];
    const int*   batch = (const int*)  d_in[3];
    const float* Wn    = (const float*)d_in[4];
    const float* bn    = (const float*)d_in[5];
    const float* We    = (const float*)d_in[6];
    const float* be    = (const float*)d_in[7];
    const float* Wnn   = (const float*)d_in[8];
    const float* bnn   = (const float*)d_in[9];
    const float* Wroot = (const float*)d_in[10];
    const float* bconv = (const float*)d_in[11];
    const float* W1    = (const float*)d_in[12];
    const float* b1    = (const float*)d_in[13];
    const float* W2    = (const float*)d_in[14];
    const float* b2    = (const float*)d_in[15];
    const float* W3    = (const float*)d_in[16];
    const float* b3    = (const float*)d_in[17];
    float* out = (float*)d_out;

    // ws: s0 | s1 | hist | pooled | cursor | rank | bfrag | msg | bar
    float* s0     = (float*)d_ws;                         // N*H f32
    float* s1     = s0 + N_NODES * H;                     // N*H f32
    int*   hist   = (int*)(s1 + N_NODES * H);             // N
    float* pooled = (float*)(hist + N_NODES);             // G*H
    int*   cursor = (int*)(pooled + G_GRAPHS * H);        // N
    int*   rank   = cursor + N_NODES;                     // E
    unsigned short* bfrag = (unsigned short*)(rank + N_EDGES); // 3*66*512
    unsigned short* msg   = bfrag + 3 * NSTEP * 512;      // E*H bf16
    int*   bar    = (int*)(msg + (size_t)N_EDGES * H);    // 2 ints

    (void)hipMemsetAsync(bar, 0, 2 * sizeof(int), stream);

    mega_k<<<NBLK, NTHR, 0, stream>>>(
        x, ei, eattr, batch, Wn, bn, We, be, Wnn, bnn, Wroot, bconv,
        W1, b1, W2, b2, W3, b3, out,
        s0, s1, hist, pooled, cursor, rank, bfrag, msg, bar);
}

// Round 9
// 135.576 us; speedup vs baseline: 15.9445x; 15.9445x over previous
//
#include <hip/hip_runtime.h>
#include <hip/hip_bf16.h>

#define N_NODES 30000
#define N_EDGES 120000
#define IN_DIM  9
#define H       32
#define G_GRAPHS 256
#define NSTEP   66            // K = 33*32 = 1056, K-step 16

#define ZERO_ELEMS   (N_NODES * H + G_GRAPHS * H)     // agg + pooled
#define ZERO_BLOCKS  ((ZERO_ELEMS + 255) / 256)       // 3782
#define EMBED_BLOCKS 3750                             // 960000/256
#define WCONV_BLOCKS 396                              // 3*66*512/256

typedef __attribute__((ext_vector_type(2)))  __fp16 half2v;
typedef __attribute__((ext_vector_type(8)))  __fp16 half8v;
typedef __attribute__((ext_vector_type(16))) float f32x16;

// ------------- fused prologue: zero(agg|pooled) | node embed | weight conv
__global__ __launch_bounds__(256) void prologue_k(
    float* __restrict__ agg, float* __restrict__ pooled,
    const float* __restrict__ x, const float* __restrict__ Wn,
    const float* __restrict__ bn, float* __restrict__ s,
    const float* __restrict__ Wnn, const float* __restrict__ bnn,
    __fp16* __restrict__ wf)
{
    const int b = blockIdx.x;
    if (b < ZERO_BLOCKS) {
        int i = b * 256 + threadIdx.x;
        if (i < N_NODES * H)    agg[i] = 0.f;
        else if (i < ZERO_ELEMS) pooled[i - N_NODES * H] = 0.f;
    } else if (b < ZERO_BLOCKS + EMBED_BLOCKS) {
        int gid = (b - ZERO_BLOCKS) * 256 + threadIdx.x;   // < 960000 exactly
        int n = gid >> 5, o = gid & 31;
        float acc = bn[o];
        #pragma unroll
        for (int i = 0; i < IN_DIM; ++i)
            acc = fmaf(x[n * IN_DIM + i], Wn[i * H + o], acc);
        s[gid] = fmaxf(acc, 0.f);
    } else {
        // wf[k][step][lane][t] = f16(Wf_k[step*16 + (lane>>5)*8 + t , lane&31])
        // Wf_k = [Wnn_k (1024x32); bnn_k (32x32)]
        int gid = (b - ZERO_BLOCKS - EMBED_BLOCKS) * 256 + threadIdx.x; // < 101376
        int layer = gid / (NSTEP * 512);
        int rem   = gid % (NSTEP * 512);
        int step  = rem >> 9;
        int lane  = (rem >> 3) & 63;
        int t     = gid & 7;
        int krow  = step * 16 + ((lane >> 5) << 3) + t;   // 0..1055
        int col   = lane & 31;
        float v = (krow < 1024) ? Wnn[layer * 32768 + krow * 32 + col]
                                : bnn[layer * 1024 + (krow - 1024) * 32 + col];
        wf[gid] = (__fp16)v;
    }
}

// ------------------------------------------------------------ edge conv MFMA
// Streaming edge order (coalesced reads), atomic scatter-add to agg (R2-proven:
// only 3.84MB of distinct dst lines/layer -> L2 merges most traffic).
// A-frag: row=lane&31 (edge), k=(lane>>5)*8+t
// D-frag: col=lane&31 (=o), row=(reg&3)+8*(reg>>2)+4*(lane>>5)
__global__ __launch_bounds__(256) void edge_mfma_k(
    const float* __restrict__ s, const float* __restrict__ eattr,
    const int* __restrict__ ei, const float* __restrict__ We,
    const float* __restrict__ be, const __fp16* __restrict__ wf,
    float* __restrict__ agg)
{
    const int wave = threadIdx.x >> 6;
    const int lane = threadIdx.x & 63;
    const int ebase = blockIdx.x * 256 + wave * 64;   // 120000 % 64 == 0
    if (ebase >= N_EDGES) return;
    const int er = lane & 31;
    const int hi = lane >> 5;

    const int e0 = ebase + er;
    const int e1 = ebase + 32 + er;

    const float a00 = eattr[e0*3+0], a01 = eattr[e0*3+1], a02 = eattr[e0*3+2];
    const float a10 = eattr[e1*3+0], a11 = eattr[e1*3+1], a12 = eattr[e1*3+2];

    const int src0 = ei[e0], src1 = ei[e1];

    // h rows as f16 pairs: hp0/hp1[q] = (h[2q], h[2q+1]) over the 16 values
    // this lane contributes (i = (step&1)*16 + hi*8 + t)
    half2v hp0[8], hp1[8];
    {
        const float* r0 = s + src0 * H + hi * 8;
        const float* r1 = s + src1 * H + hi * 8;
        #pragma unroll
        for (int q = 0; q < 2; ++q) {
            float4 u0 = *(const float4*)(r0 + q * 16);
            float4 u1 = *(const float4*)(r0 + q * 16 + 4);
            float4 v0 = *(const float4*)(r1 + q * 16);
            float4 v1 = *(const float4*)(r1 + q * 16 + 4);
            hp0[q*4+0] = __builtin_amdgcn_cvt_pkrtz(u0.x, u0.y);
            hp0[q*4+1] = __builtin_amdgcn_cvt_pkrtz(u0.z, u0.w);
            hp0[q*4+2] = __builtin_amdgcn_cvt_pkrtz(u1.x, u1.y);
            hp0[q*4+3] = __builtin_amdgcn_cvt_pkrtz(u1.z, u1.w);
            hp1[q*4+0] = __builtin_amdgcn_cvt_pkrtz(v0.x, v0.y);
            hp1[q*4+1] = __builtin_amdgcn_cvt_pkrtz(v0.z, v0.w);
            hp1[q*4+2] = __builtin_amdgcn_cvt_pkrtz(v1.x, v1.y);
            hp1[q*4+3] = __builtin_amdgcn_cvt_pkrtz(v1.z, v1.w);
        }
    }

    f32x16 acc0 = {};
    f32x16 acc1 = {};
    half2v ea0 = {(__fp16)1.f, (__fp16)1.f};
    half2v ea1 = ea0;

    #pragma unroll
    for (int step = 0; step < NSTEP; ++step) {
        const int j = step >> 1;               // compile-time after unroll
        if ((step & 1) == 0 && j < 32) {
            const float w0 = We[j], w1 = We[32+j], w2 = We[64+j], bb = be[j];
            float f0 = fmaxf(fmaf(a02, w2, fmaf(a01, w1, fmaf(a00, w0, bb))), 0.f);
            float f1 = fmaxf(fmaf(a12, w2, fmaf(a11, w1, fmaf(a10, w0, bb))), 0.f);
            ea0 = __builtin_amdgcn_cvt_pkrtz(f0, f0);
            ea1 = __builtin_amdgcn_cvt_pkrtz(f1, f1);
        }
        const int sel = (step & 1) * 4;
        half8v A0, A1;
        if (j < 32) {
            #pragma unroll
            for (int q = 0; q < 4; ++q) {
                half2v m0 = ea0 * hp0[sel + q];   // v_pk_mul_f16
                half2v m1 = ea1 * hp1[sel + q];
                A0[2*q]   = m0[0]; A0[2*q+1] = m0[1];
                A1[2*q]   = m1[0]; A1[2*q+1] = m1[1];
            }
        } else {                                   // bnn rows: ea == 1
            #pragma unroll
            for (int q = 0; q < 4; ++q) {
                A0[2*q]   = hp0[sel+q][0]; A0[2*q+1] = hp0[sel+q][1];
                A1[2*q]   = hp1[sel+q][0]; A1[2*q+1] = hp1[sel+q][1];
            }
        }
        const half8v B = *(const half8v*)(wf + ((step * 64 + lane) << 3));
        acc0 = __builtin_amdgcn_mfma_f32_32x32x16_f16(A0, B, acc0, 0, 0, 0);
        acc1 = __builtin_amdgcn_mfma_f32_32x32x16_f16(A1, B, acc1, 0, 0, 0);
    }

    const int* dsts = ei + N_EDGES;
    const int o = er;
    #pragma unroll
    for (int reg = 0; reg < 16; ++reg) {
        const int r = (reg & 3) + 8 * (reg >> 2) + 4 * hi;
        const int d0 = dsts[ebase + r];
        const int d1 = dsts[ebase + 32 + r];
        atomicAdd(agg + d0 * H + o, acc0[reg]);
        atomicAdd(agg + d1 * H + o, acc1[reg]);
    }
}

// ---------- fused root + relu + residual, agg:=0 (+pool on last layer)
__global__ __launch_bounds__(256) void finalize_k(
    float* __restrict__ agg, const float* __restrict__ sin,
    const float* __restrict__ Wroot, const float* __restrict__ bconv,
    float* __restrict__ sout, const int* __restrict__ batch,
    float* __restrict__ pooled, int do_pool)
{
    int gid = blockIdx.x * 256 + threadIdx.x;
    if (gid >= N_NODES * H) return;
    int n = gid >> 5, o = gid & 31;
    float a = agg[gid];
    agg[gid] = 0.f;                           // re-arm for next layer
    float acc = bconv[o];
    const float* row = sin + n * H;
    #pragma unroll
    for (int i = 0; i < H; ++i)
        acc = fmaf(row[i], Wroot[i * H + o], acc);
    float val = fmaxf(a + acc, 0.f) + sin[gid];
    if (do_pool)
        atomicAdd(pooled + batch[n] * H + o, val);
    else
        sout[gid] = val;
}

// ---------------------------------------------------------------- MLP head
__global__ __launch_bounds__(128) void mlp_k(
    const float* __restrict__ pooled,
    const float* __restrict__ W1, const float* __restrict__ b1,
    const float* __restrict__ W2, const float* __restrict__ b2,
    const float* __restrict__ W3, const float* __restrict__ b3,
    float* __restrict__ out)
{
    __shared__ float p[H];
    __shared__ float h1[128];
    __shared__ float h2[64];
    const int g = blockIdx.x, t = threadIdx.x;
    if (t < H) p[t] = pooled[g * H + t];
    __syncthreads();
    float a = b1[t];
    #pragma unroll
    for (int i = 0; i < H; ++i)
        a = fmaf(p[i], W1[i * 128 + t], a);
    h1[t] = fmaxf(a, 0.f);
    __syncthreads();
    if (t < 64) {
        float a2 = b2[t];
        #pragma unroll 4
        for (int i = 0; i < 128; ++i)
            a2 = fmaf(h1[i], W2[i * 64 + t], a2);
        h2[t] = fmaxf(a2, 0.f);
    }
    __syncthreads();
    if (t < 64) {
        float v = h2[t] * W3[t];
        #pragma unroll
        for (int off = 32; off > 0; off >>= 1)
            v += __shfl_down(v, off);
        if (t == 0) out[g] = v + b3[0];
    }
}

// ---------------------------------------------------------------- launcher
extern "C" void kernel_launch(void* const* d_in, const int* in_sizes, int n_in,
                              void* d_out, int out_size, void* d_ws, size_t ws_size,
                              hipStream_t stream)
{
    const float* x     = (const float*)d_in[0];
    const int*   ei    = (const int*)  d_in[1];
    const float* eattr = (const float*)d_in[2];
    const int*   batch = (const int*)  d_in[3];
    const float* Wn    = (const float*)d_in[4];
    const float* bn    = (const float*)d_in[5];
    const float* We    = (const float*)d_in[6];
    const float* be    = (const float*)d_in[7];
    const float* Wnn   = (const float*)d_in[8];
    const float* bnn   = (const float*)d_in[9];
    const float* Wroot = (const float*)d_in[10];
    const float* bconv = (const float*)d_in[11];
    const float* W1    = (const float*)d_in[12];
    const float* b1    = (const float*)d_in[13];
    const float* W2    = (const float*)d_in[14];
    const float* b2    = (const float*)d_in[15];
    const float* W3    = (const float*)d_in[16];
    const float* b3    = (const float*)d_in[17];
    float* out = (float*)d_out;

    // ws: s0 | s1 | agg | pooled | wf16
    float* s0     = (float*)d_ws;                         // N*H f32
    float* s1     = s0 + N_NODES * H;                     // N*H f32
    float* agg    = s1 + N_NODES * H;                     // N*H f32
    float* pooled = agg + N_NODES * H;                    // G*H f32
    __fp16* wf    = (__fp16*)(pooled + G_GRAPHS * H);     // 3*66*512 f16

    const int nw_grid = (N_NODES * H + 255) / 256;   // 3750
    const int e_grid  = (N_EDGES + 255) / 256;       // 469

    prologue_k<<<ZERO_BLOCKS + EMBED_BLOCKS + WCONV_BLOCKS, 256, 0, stream>>>(
        agg, pooled, x, Wn, bn, s0, Wnn, bnn, wf);

    const float* sin = s0;
    float* sout = s1;
    for (int k = 0; k < 3; ++k) {
        edge_mfma_k<<<e_grid, 256, 0, stream>>>(sin, eattr, ei, We, be,
                                                wf + k * NSTEP * 512, agg);
        finalize_k<<<nw_grid, 256, 0, stream>>>(agg, sin,
                                                Wroot + k * H * H,
                                                bconv + k * H, sout,
                                                batch, pooled, (k == 2) ? 1 : 0);
        const float* tmp = sout; sout = (float*)sin; sin = tmp;
    }

    mlp_k<<<G_GRAPHS, 128, 0, stream>>>(pooled, W1, b1, W2, b2, W3, b3, out);
}